// Round 1
// baseline (389.985 us; speedup 1.0000x reference)
//
#include <hip/hip_runtime.h>

#define NG   16
#define HID  256

// Output layout (floats): visit | tokens | weights
constexpr size_t BT        = 32ull * 2048ull;          // 65536 (b,t) rows
constexpr size_t VISIT_OFF = 0;
constexpr size_t TOK_OFF   = BT * HID;                 // 16,777,216
constexpr size_t WT_OFF    = TOK_OFF + BT * NG * HID;  // 285,212,672

__device__ __forceinline__ float fast_tanh(float v) {
    // tanh(x) = 1 - 2/(exp(2x)+1); v_exp/v_rcp are ~1ulp, threshold is 3.7e-2
    float e = __expf(2.0f * v);
    return 1.0f - 2.0f * __builtin_amdgcn_rcpf(e + 1.0f);
}

__global__ __launch_bounds__(256) void gve_kernel(
    const float* __restrict__ x,      // (B,T,64)
    const float* __restrict__ w_gp,   // (256)
    const float* __restrict__ b_gp,   // (256)
    const float* __restrict__ w_sp,   // (256)
    const float* __restrict__ b_sp,   // scalar
    float* __restrict__ out)
{
    const int idx  = blockIdx.x;      // b*2048 + t
    const int h    = threadIdx.x;     // 0..255 = hidden index
    const int lane = h & 63;
    const int wv   = h >> 6;          // wave 0..3

    __shared__ float sx[64];
    __shared__ float sred[4][NG];
    __shared__ float ssc[NG];
    __shared__ float swt[NG];
    __shared__ float sgv[NG];

    // ---- stage x row ----
    if (h < 64) sx[h] = x[(size_t)idx * 64 + h];
    __syncthreads();

    // ---- group means (groups = contiguous runs, sizes [1,3,5,7] tiled x4) ----
    if (h < NG) {
        const int szs[4]  = {1, 3, 5, 7};
        const int pref[4] = {0, 1, 4, 9};
        const int sz  = szs[h & 3];
        const int off = ((h >> 2) << 4) + pref[h & 3];
        float s = 0.0f;
        #pragma unroll
        for (int i = 0; i < 7; ++i)
            if (i < sz) s += sx[off + i];
        sgv[h] = s / (float)sz;
    }
    __syncthreads();

    float gv[NG];
    #pragma unroll
    for (int g = 0; g < NG; ++g) gv[g] = sgv[g];

    const float wg = w_gp[h];
    const float bg = b_gp[h];
    const float ws = w_sp[h];

    // ---- per-thread score partials: tanh(token[g][h]) * w_sp[h] ----
    float part[NG];
    #pragma unroll
    for (int g = 0; g < NG; ++g) {
        const float tok = fmaf(gv[g], wg, bg);
        part[g] = fast_tanh(tok) * ws;
    }

    // ---- split butterfly reduction over 64 lanes (32 shuffles, not 96) ----
    #pragma unroll
    for (int g = 0; g < NG; ++g) part[g] += __shfl_xor(part[g], 32, 64);
    const bool b5 = (lane & 32) != 0;
    float v8[8];
    #pragma unroll
    for (int j = 0; j < 8; ++j) v8[j] = b5 ? part[j + 8] : part[j];
    #pragma unroll
    for (int j = 0; j < 8; ++j) v8[j] += __shfl_xor(v8[j], 16, 64);
    const bool b4 = (lane & 16) != 0;
    float v4_[4];
    #pragma unroll
    for (int j = 0; j < 4; ++j) v4_[j] = b4 ? v8[j + 4] : v8[j];
    #pragma unroll
    for (int j = 0; j < 4; ++j) v4_[j] += __shfl_xor(v4_[j], 8, 64);
    const bool b3 = (lane & 8) != 0;
    float v2_[2];
    #pragma unroll
    for (int j = 0; j < 2; ++j) v2_[j] = b3 ? v4_[j + 2] : v4_[j];
    #pragma unroll
    for (int j = 0; j < 2; ++j) v2_[j] += __shfl_xor(v2_[j], 4, 64);
    const bool b2 = (lane & 4) != 0;
    float v1 = b2 ? v2_[1] : v2_[0];
    v1 += __shfl_xor(v1, 2, 64);
    v1 += __shfl_xor(v1, 1, 64);
    // lane l holds this wave's sum for group g = l>>2
    if ((lane & 3) == 0) sred[wv][lane >> 2] = v1;
    __syncthreads();

    // ---- scores + softmax (16 lanes of wave 0, lockstep-safe) ----
    if (h < NG) {
        ssc[h] = sred[0][h] + sred[1][h] + sred[2][h] + sred[3][h] + b_sp[0];
    }
    __syncthreads();
    if (h < NG) {
        float m = ssc[0];
        #pragma unroll
        for (int g = 1; g < NG; ++g) m = fmaxf(m, ssc[g]);
        swt[h] = __expf(ssc[h] - m);
    }
    __syncthreads();
    if (h < NG) {
        float s = 0.0f;
        #pragma unroll
        for (int g = 0; g < NG; ++g) s += swt[g];   // all loads precede the
        const float w = swt[h] / s;                 // dependent store (1 wave)
        out[WT_OFF + (size_t)idx * NG + h] = w;
        swt[h] = w;
    }
    __syncthreads();

    float wt[NG];
    #pragma unroll
    for (int g = 0; g < NG; ++g) wt[g] = swt[g];

    // ---- tokens (recompute: 1 FMA) + visit ----
    float visit = 0.0f;
    float* __restrict__ tokp = out + TOK_OFF + (size_t)idx * (NG * HID);
    #pragma unroll
    for (int g = 0; g < NG; ++g) {
        const float tok = fmaf(gv[g], wg, bg);
        tokp[g * HID + h] = tok;                    // 256 consecutive floats/g
        visit = fmaf(wt[g], tok, visit);
    }
    out[VISIT_OFF + (size_t)idx * HID + h] = visit;
}

extern "C" void kernel_launch(void* const* d_in, const int* in_sizes, int n_in,
                              void* d_out, int out_size, void* d_ws, size_t ws_size,
                              hipStream_t stream) {
    (void)in_sizes; (void)n_in; (void)out_size; (void)d_ws; (void)ws_size;
    const float* x    = (const float*)d_in[0];
    const float* w_gp = (const float*)d_in[1];
    const float* b_gp = (const float*)d_in[2];
    const float* w_sp = (const float*)d_in[3];
    const float* b_sp = (const float*)d_in[4];
    float* out = (float*)d_out;

    gve_kernel<<<dim3((unsigned)BT), dim3(256), 0, stream>>>(
        x, w_gp, b_gp, w_sp, b_sp, out);
}

// Round 2
// 232.861 us; speedup vs baseline: 1.6748x; 1.6748x over previous
//
#include <hip/hip_runtime.h>

#define NG   16
#define HID  256

// Output layout (floats): visit (BT,256) | tokens (BT,16,256) | weights (BT,16)
constexpr size_t BT      = 32ull * 2048ull;            // 65536 rows
constexpr size_t TOK_OFF = BT * HID;
constexpr size_t WT_OFF  = TOK_OFF + BT * NG * HID;

__device__ __forceinline__ float fast_tanh(float v) {
    // tanh(x) = 1 - 2/(exp(2x)+1); ~1ulp exp/rcp, output threshold 3.7e-2
    float e = __expf(2.0f * v);
    return 1.0f - 2.0f * __builtin_amdgcn_rcpf(e + 1.0f);
}

__global__ __launch_bounds__(256) void gve_kernel(
    const float*  __restrict__ x,      // (BT,64)
    const float4* __restrict__ w_gp4,  // (64) float4
    const float4* __restrict__ b_gp4,
    const float4* __restrict__ w_sp4,
    const float*  __restrict__ b_sp,
    float* __restrict__ out)
{
    const int lane = threadIdx.x & 63;
    const int wv   = threadIdx.x >> 6;
    const size_t row = (size_t)blockIdx.x * 4 + wv;   // one (b,t) row per wave

    // ---- stage x row (per-wave slot; one cheap block barrier) ----
    __shared__ float sx[4][64];
    sx[wv][lane] = x[row * 64 + lane];
    __syncthreads();

    // ---- group means: contiguous segments, sizes [1,3,5,7] tiled x4 ----
    // per-16 chunk boundaries: 0,1,4,9,16
    float gv[NG];
    {
        const float rcnt[4] = {1.0f, 1.0f/3.0f, 0.2f, 1.0f/7.0f};
        #pragma unroll
        for (int g = 0; g < NG; ++g) {
            const int chunk = g >> 2, sub = g & 3;
            const int begs[5] = {0, 1, 4, 9, 16};
            const int beg = chunk * 16 + begs[sub];
            const int end = chunk * 16 + begs[sub + 1];
            float s = 0.0f;
            #pragma unroll
            for (int i = beg; i < end; ++i) s += sx[wv][i];   // uniform addr: broadcast
            gv[g] = s * rcnt[sub];
        }
    }

    // ---- per-lane hidden slice: h = 4*lane .. 4*lane+3 ----
    const float4 wg = w_gp4[lane];
    const float4 bg = b_gp4[lane];
    const float4 ws = w_sp4[lane];

    // ---- score partials: sum over this lane's 4 h of tanh(tok)*w_sp ----
    float part[NG];
    #pragma unroll
    for (int g = 0; g < NG; ++g) {
        float tx = fmaf(gv[g], wg.x, bg.x);
        float ty = fmaf(gv[g], wg.y, bg.y);
        float tz = fmaf(gv[g], wg.z, bg.z);
        float tw = fmaf(gv[g], wg.w, bg.w);
        part[g] = fast_tanh(tx) * ws.x + fast_tanh(ty) * ws.y
                + fast_tanh(tz) * ws.z + fast_tanh(tw) * ws.w;
    }

    // ---- split butterfly reduce over 64 lanes (32 shuffles) ----
    #pragma unroll
    for (int g = 0; g < NG; ++g) part[g] += __shfl_xor(part[g], 32, 64);
    const bool b5 = (lane & 32) != 0;
    float v8[8];
    #pragma unroll
    for (int j = 0; j < 8; ++j) v8[j] = b5 ? part[j + 8] : part[j];
    #pragma unroll
    for (int j = 0; j < 8; ++j) v8[j] += __shfl_xor(v8[j], 16, 64);
    const bool b4 = (lane & 16) != 0;
    float v4_[4];
    #pragma unroll
    for (int j = 0; j < 4; ++j) v4_[j] = b4 ? v8[j + 4] : v8[j];
    #pragma unroll
    for (int j = 0; j < 4; ++j) v4_[j] += __shfl_xor(v4_[j], 8, 64);
    const bool b3 = (lane & 8) != 0;
    float v2_[2];
    #pragma unroll
    for (int j = 0; j < 2; ++j) v2_[j] = b3 ? v4_[j + 2] : v4_[j];
    #pragma unroll
    for (int j = 0; j < 2; ++j) v2_[j] += __shfl_xor(v2_[j], 4, 64);
    const bool b2 = (lane & 4) != 0;
    float v1 = b2 ? v2_[1] : v2_[0];
    v1 += __shfl_xor(v1, 2, 64);
    v1 += __shfl_xor(v1, 1, 64);
    // every lane now holds score-sum for group g = lane>>2

    // ---- softmax, fully in-register ----
    const float score = v1 + b_sp[0];
    float m = score;
    m = fmaxf(m, __shfl_xor(m, 4, 64));
    m = fmaxf(m, __shfl_xor(m, 8, 64));
    m = fmaxf(m, __shfl_xor(m, 16, 64));
    m = fmaxf(m, __shfl_xor(m, 32, 64));          // max over all 16 groups
    float e = __expf(score - m);
    float s = e;
    s += __shfl_xor(s, 4, 64);
    s += __shfl_xor(s, 8, 64);
    s += __shfl_xor(s, 16, 64);
    s += __shfl_xor(s, 32, 64);                   // sum: exactly one lane per g
    const float w = e / s;                        // weight for g = lane>>2

    // gather all 16 weights (compile-time source lanes -> registers)
    float wt[NG];
    #pragma unroll
    for (int g = 0; g < NG; ++g) wt[g] = __shfl(w, 4 * g, 64);

    // ---- tokens (recompute, float4 stores) + visit accumulate ----
    float4 visit; visit.x = visit.y = visit.z = visit.w = 0.0f;
    float* __restrict__ tokp = out + TOK_OFF + row * (NG * HID) + 4 * lane;
    #pragma unroll
    for (int g = 0; g < NG; ++g) {
        float4 t;
        t.x = fmaf(gv[g], wg.x, bg.x);
        t.y = fmaf(gv[g], wg.y, bg.y);
        t.z = fmaf(gv[g], wg.z, bg.z);
        t.w = fmaf(gv[g], wg.w, bg.w);
        *(float4*)(tokp + g * HID) = t;           // 1 KB per wave-store
        visit.x = fmaf(wt[g], t.x, visit.x);
        visit.y = fmaf(wt[g], t.y, visit.y);
        visit.z = fmaf(wt[g], t.z, visit.z);
        visit.w = fmaf(wt[g], t.w, visit.w);
    }
    *(float4*)(out + row * HID + 4 * lane) = visit;

    // ---- weights: 16 lanes scalar-store (64 B per row) ----
    const float wl = __shfl(w, (lane & 15) * 4, 64);   // bpermute gather
    if (lane < NG) out[WT_OFF + row * NG + lane] = wl;
}

extern "C" void kernel_launch(void* const* d_in, const int* in_sizes, int n_in,
                              void* d_out, int out_size, void* d_ws, size_t ws_size,
                              hipStream_t stream) {
    (void)in_sizes; (void)n_in; (void)out_size; (void)d_ws; (void)ws_size;
    const float*  x    = (const float*)d_in[0];
    const float4* w_gp = (const float4*)d_in[1];
    const float4* b_gp = (const float4*)d_in[2];
    const float4* w_sp = (const float4*)d_in[3];
    const float*  b_sp = (const float*)d_in[4];
    float* out = (float*)d_out;

    gve_kernel<<<dim3((unsigned)(BT / 4)), dim3(256), 0, stream>>>(
        x, w_gp, b_gp, w_sp, b_sp, out);
}

// Round 3
// 231.079 us; speedup vs baseline: 1.6877x; 1.0077x over previous
//
#include <hip/hip_runtime.h>

#define NG   16
#define HID  256

typedef float f32x4 __attribute__((ext_vector_type(4)));

// Output layout (floats): visit (BT,256) | tokens (BT,16,256) | weights (BT,16)
constexpr size_t BT      = 32ull * 2048ull;            // 65536 rows
constexpr size_t TOK_OFF = BT * HID;
constexpr size_t WT_OFF  = TOK_OFF + BT * NG * HID;

__device__ __forceinline__ float fast_tanh(float v) {
    // tanh(x) = 1 - 2/(exp(2x)+1); ~1ulp exp/rcp, output threshold 3.7e-2
    float e = __expf(2.0f * v);
    return 1.0f - 2.0f * __builtin_amdgcn_rcpf(e + 1.0f);
}

__global__ __launch_bounds__(256) void gve_kernel(
    const float*  __restrict__ x,      // (BT,64)
    const f32x4*  __restrict__ w_gp4,  // (64) float4
    const f32x4*  __restrict__ b_gp4,
    const f32x4*  __restrict__ w_sp4,
    const float*  __restrict__ b_sp,
    float* __restrict__ out)
{
    const int lane = threadIdx.x & 63;
    const int wv   = threadIdx.x >> 6;
    const size_t row = (size_t)blockIdx.x * 4 + wv;   // one (b,t) row per wave

    // ---- stage x row (per-wave slot) ----
    __shared__ float sx[4][64];
    sx[wv][lane] = x[row * 64 + lane];
    __syncthreads();

    // ---- group means: contiguous segments, sizes [1,3,5,7] tiled x4 ----
    float gv[NG];
    {
        const float rcnt[4] = {1.0f, 1.0f/3.0f, 0.2f, 1.0f/7.0f};
        #pragma unroll
        for (int g = 0; g < NG; ++g) {
            const int chunk = g >> 2, sub = g & 3;
            const int begs[5] = {0, 1, 4, 9, 16};
            const int beg = chunk * 16 + begs[sub];
            const int end = chunk * 16 + begs[sub + 1];
            float s = 0.0f;
            #pragma unroll
            for (int i = beg; i < end; ++i) s += sx[wv][i];   // uniform addr: broadcast
            gv[g] = s * rcnt[sub];
        }
    }

    // ---- per-lane hidden slice: h = 4*lane .. 4*lane+3 ----
    const f32x4 wg = w_gp4[lane];
    const f32x4 bg = b_gp4[lane];
    const f32x4 ws = w_sp4[lane];

    // ---- fused: token store (early, NT) + score partials ----
    float* __restrict__ tokp = out + TOK_OFF + row * (NG * HID) + 4 * lane;
    float part[NG];
    #pragma unroll
    for (int g = 0; g < NG; ++g) {
        f32x4 t;
        t.x = fmaf(gv[g], wg.x, bg.x);
        t.y = fmaf(gv[g], wg.y, bg.y);
        t.z = fmaf(gv[g], wg.z, bg.z);
        t.w = fmaf(gv[g], wg.w, bg.w);
        __builtin_nontemporal_store(t, (f32x4*)(tokp + g * HID));  // 1 KB/wave-store
        part[g] = fast_tanh(t.x) * ws.x + fast_tanh(t.y) * ws.y
                + fast_tanh(t.z) * ws.z + fast_tanh(t.w) * ws.w;
    }

    // ---- split butterfly reduce over 64 lanes (32 shuffles) ----
    #pragma unroll
    for (int g = 0; g < NG; ++g) part[g] += __shfl_xor(part[g], 32, 64);
    const bool b5 = (lane & 32) != 0;
    float v8[8];
    #pragma unroll
    for (int j = 0; j < 8; ++j) v8[j] = b5 ? part[j + 8] : part[j];
    #pragma unroll
    for (int j = 0; j < 8; ++j) v8[j] += __shfl_xor(v8[j], 16, 64);
    const bool b4 = (lane & 16) != 0;
    float v4_[4];
    #pragma unroll
    for (int j = 0; j < 4; ++j) v4_[j] = b4 ? v8[j + 4] : v8[j];
    #pragma unroll
    for (int j = 0; j < 4; ++j) v4_[j] += __shfl_xor(v4_[j], 8, 64);
    const bool b3 = (lane & 8) != 0;
    float v2_[2];
    #pragma unroll
    for (int j = 0; j < 2; ++j) v2_[j] = b3 ? v4_[j + 2] : v4_[j];
    #pragma unroll
    for (int j = 0; j < 2; ++j) v2_[j] += __shfl_xor(v2_[j], 4, 64);
    const bool b2 = (lane & 4) != 0;
    float v1 = b2 ? v2_[1] : v2_[0];
    v1 += __shfl_xor(v1, 2, 64);
    v1 += __shfl_xor(v1, 1, 64);
    // every lane now holds score-sum for group g = lane>>2

    // ---- softmax, fully in-register ----
    const float score = v1 + b_sp[0];
    float m = score;
    m = fmaxf(m, __shfl_xor(m, 4, 64));
    m = fmaxf(m, __shfl_xor(m, 8, 64));
    m = fmaxf(m, __shfl_xor(m, 16, 64));
    m = fmaxf(m, __shfl_xor(m, 32, 64));          // max over all 16 groups
    float e = __expf(score - m);
    float s = e;
    s += __shfl_xor(s, 4, 64);
    s += __shfl_xor(s, 8, 64);
    s += __shfl_xor(s, 16, 64);
    s += __shfl_xor(s, 32, 64);                   // sum: one lane per group
    const float w = e / s;                        // weight for g = lane>>2

    // gather all 16 weights (compile-time source lanes)
    float wt[NG];
    #pragma unroll
    for (int g = 0; g < NG; ++g) wt[g] = __shfl(w, 4 * g, 64);

    // ---- visit: recompute tokens (1 FMA each), accumulate, NT store ----
    f32x4 visit = {0.0f, 0.0f, 0.0f, 0.0f};
    #pragma unroll
    for (int g = 0; g < NG; ++g) {
        visit.x = fmaf(wt[g], fmaf(gv[g], wg.x, bg.x), visit.x);
        visit.y = fmaf(wt[g], fmaf(gv[g], wg.y, bg.y), visit.y);
        visit.z = fmaf(wt[g], fmaf(gv[g], wg.z, bg.z), visit.z);
        visit.w = fmaf(wt[g], fmaf(gv[g], wg.w, bg.w), visit.w);
    }
    __builtin_nontemporal_store(visit, (f32x4*)(out + row * HID + 4 * lane));

    // ---- weights: 16 lanes scalar NT store (64 B per row) ----
    const float wl = __shfl(w, (lane & 15) * 4, 64);
    if (lane < NG)
        __builtin_nontemporal_store(wl, out + WT_OFF + row * NG + lane);
}

extern "C" void kernel_launch(void* const* d_in, const int* in_sizes, int n_in,
                              void* d_out, int out_size, void* d_ws, size_t ws_size,
                              hipStream_t stream) {
    (void)in_sizes; (void)n_in; (void)out_size; (void)d_ws; (void)ws_size;
    const float*  x    = (const float*)d_in[0];
    const f32x4*  w_gp = (const f32x4*)d_in[1];
    const f32x4*  b_gp = (const f32x4*)d_in[2];
    const f32x4*  w_sp = (const f32x4*)d_in[3];
    const float*  b_sp = (const float*)d_in[4];
    float* out = (float*)d_out;

    gve_kernel<<<dim3((unsigned)(BT / 4)), dim3(256), 0, stream>>>(
        x, w_gp, b_gp, w_sp, b_sp, out);
}